// Round 6
// baseline (236.443 us; speedup 1.0000x reference)
//
#include <hip/hip_runtime.h>
#include <cstddef>

#define D 64
#define K 512
#define NROWS (32*64*64)       // 131072 rows
#define RPB 64                 // rows per block (vq_main)
#define NBLK (NROWS / RPB)     // 2048 blocks
#define NOUT 8388608           // NROWS * D

// ws layout (floats):
//   [0,      32768)  : eT[K][D]   transposed codebook
//   [32768,  33280)  : enorm[K]   (np-rounding-exact: sequential non-fused sum)
//   [33280,  35328)  : block partial loss sums [NBLK=2048]

__global__ __launch_bounds__(256) void vq_prep(const float* __restrict__ emb,
                                               float* __restrict__ eT,
                                               float* __restrict__ enorm) {
    const int k = blockIdx.x * blockDim.x + threadIdx.x;
    if (k >= K) return;
    // np.sum(emb*emb, axis=0): axis-0 reduce = sequential row sweep over
    // individually-rounded products. Replicate exactly (no FMA contraction).
    float nrm = 0.f;
#pragma unroll
    for (int d = 0; d < D; ++d) {
        const float v = emb[d * K + k];   // coalesced across k
        nrm = __fadd_rn(nrm, __fmul_rn(v, v));
        eT[k * D + d] = v;
    }
    enorm[k] = nrm;
}

// Round-6 structure: r2-r5 post-mortems proved the allocator will always
// spill a 64-wide loop-invariant register array (VGPR_Count pinned at 48-64,
// scratch reloads ~= 100us of stalls, immune to launch_bounds AND
// amdgpu_waves_per_eu). So: x lives in LDS TRANSPOSED (xT[d][row], lane=row
// -> stride-4B = conflict-free ds_read_b32 with imm offsets), read
// just-in-time per dim and reused across 8 codes. Peak register demand ~55
// (32 loop-carried accumulators -- which the allocator never spills) fits
// INSIDE its preferred 64-VGPR budget. Codebook stays on the scalar path.
__global__ __launch_bounds__(256) void vq_main(const float* __restrict__ x,
                                               const float* __restrict__ eT,
                                               const float* __restrict__ enorm,
                                               float* __restrict__ out,
                                               float* __restrict__ partials) {
    __shared__ float xT[D][RPB];     // 16 KB transposed x tile
    __shared__ float s_dist[256];
    __shared__ int   s_idx[256];
    __shared__ int   s_code[RPB];
    __shared__ float s_red[4];

    const int t    = threadIdx.x;
    const int wave = t >> 6;
    const int lane = t & 63;                    // = local row for the scan phase
    const size_t rowbase = (size_t)blockIdx.x * RPB;

    // ---- stage x tile into LDS, transposed ----
    // wave w loads dim-quarter 16w..16w+15 of all 64 rows: lane reads 64
    // contiguous bytes of its row (4x float4); LDS writes are stride-4B
    // across lanes (banks 0..31 x2 = free).
    {
        const float4* __restrict__ src = (const float4*)(x + (rowbase + lane) * D + wave * 16);
        const float4 v0 = src[0], v1 = src[1], v2 = src[2], v3 = src[3];
        const int d0 = wave * 16;
        xT[d0+ 0][lane] = v0.x; xT[d0+ 1][lane] = v0.y; xT[d0+ 2][lane] = v0.z; xT[d0+ 3][lane] = v0.w;
        xT[d0+ 4][lane] = v1.x; xT[d0+ 5][lane] = v1.y; xT[d0+ 6][lane] = v1.z; xT[d0+ 7][lane] = v1.w;
        xT[d0+ 8][lane] = v2.x; xT[d0+ 9][lane] = v2.y; xT[d0+10][lane] = v2.z; xT[d0+11][lane] = v2.w;
        xT[d0+12][lane] = v3.x; xT[d0+13][lane] = v3.y; xT[d0+14][lane] = v3.z; xT[d0+15][lane] = v3.w;
    }
    __syncthreads();

    // ---- xnorm: replicate numpy pairwise_sum for n=64 exactly (from LDS) ----
    // r[j]=p[j]; for b=1..7: r[j]+=p[8b+j]; then ((r0+r1)+(r2+r3))+((r4+r5)+(r6+r7)),
    // p[i] = fl(x_i*x_i). __fmul_rn/__fadd_rn forbid FMA contraction.
    float r0, r1, r2, r3, r4, r5, r6, r7;
    {
        float v;
        v = xT[0][lane]; r0 = __fmul_rn(v, v);
        v = xT[1][lane]; r1 = __fmul_rn(v, v);
        v = xT[2][lane]; r2 = __fmul_rn(v, v);
        v = xT[3][lane]; r3 = __fmul_rn(v, v);
        v = xT[4][lane]; r4 = __fmul_rn(v, v);
        v = xT[5][lane]; r5 = __fmul_rn(v, v);
        v = xT[6][lane]; r6 = __fmul_rn(v, v);
        v = xT[7][lane]; r7 = __fmul_rn(v, v);
#pragma unroll
        for (int b = 1; b < 8; ++b) {
            v = xT[8*b+0][lane]; r0 = __fadd_rn(r0, __fmul_rn(v, v));
            v = xT[8*b+1][lane]; r1 = __fadd_rn(r1, __fmul_rn(v, v));
            v = xT[8*b+2][lane]; r2 = __fadd_rn(r2, __fmul_rn(v, v));
            v = xT[8*b+3][lane]; r3 = __fadd_rn(r3, __fmul_rn(v, v));
            v = xT[8*b+4][lane]; r4 = __fadd_rn(r4, __fmul_rn(v, v));
            v = xT[8*b+5][lane]; r5 = __fadd_rn(r5, __fmul_rn(v, v));
            v = xT[8*b+6][lane]; r6 = __fadd_rn(r6, __fmul_rn(v, v));
            v = xT[8*b+7][lane]; r7 = __fadd_rn(r7, __fmul_rn(v, v));
        }
    }
    const float xnorm = __fadd_rn(__fadd_rn(__fadd_rn(r0, r1), __fadd_rn(r2, r3)),
                                  __fadd_rn(__fadd_rn(r4, r5), __fadd_rn(r6, r7)));

    // ---- scan this wave's QUARTER of the codebook (128 codes), 8 codes/group ----
    // Per code c: chain acc[c][m] = sum_j x[4j+m]*e[4j+m] (16 deep), combined
    // ((a0+a1)+(a2+a3)); d = fl(fl(xnorm - fl(2*dot)) + enorm) -- rounding
    // bit-identical to the verified r2/r3/r5 kernels (grouping changes only
    // which codes are in flight, not per-code arithmetic). x values read
    // just-in-time from LDS (4 transient regs); e on the scalar/s_load path.
    const int kbase = __builtin_amdgcn_readfirstlane(wave << 7);  // wave*128
    float best = 3.4028235e38f;
    int   bidx = 0;
#pragma unroll 1
    for (int g = 0; g < 16; ++g) {
        const int kc = kbase + g * 8;
        const float* __restrict__ eg = eT + (size_t)kc * D;
        float acc[8][4];
#pragma unroll
        for (int c = 0; c < 8; ++c) {
            acc[c][0] = 0.f; acc[c][1] = 0.f; acc[c][2] = 0.f; acc[c][3] = 0.f;
        }
#pragma unroll
        for (int j = 0; j < 16; ++j) {
            const float x0 = xT[4*j+0][lane];
            const float x1 = xT[4*j+1][lane];
            const float x2 = xT[4*j+2][lane];
            const float x3 = xT[4*j+3][lane];
#pragma unroll
            for (int c = 0; c < 8; ++c) {
                const float4 v = *(const float4*)(eg + (size_t)c * D + 4*j);  // wave-uniform -> s_load
                acc[c][0] = fmaf(x0, v.x, acc[c][0]);
                acc[c][1] = fmaf(x1, v.y, acc[c][1]);
                acc[c][2] = fmaf(x2, v.z, acc[c][2]);
                acc[c][3] = fmaf(x3, v.w, acc[c][3]);
            }
        }
#pragma unroll
        for (int c = 0; c < 8; ++c) {
            const float dot = __fadd_rn(__fadd_rn(acc[c][0], acc[c][1]),
                                        __fadd_rn(acc[c][2], acc[c][3]));
            const float dd = __fadd_rn(__fsub_rn(xnorm, __fmul_rn(2.f, dot)), enorm[kc + c]);
            // ascending scan + strict < keeps the FIRST minimum (np.argmin tie-break)
            if (dd < best) { best = dd; bidx = kc + c; }
        }
    }

    // ---- combine the 4 K-quarters per row ----
    s_dist[t] = best;
    s_idx[t]  = bidx;
    __syncthreads();
    if (t < RPB) {
        float bb = s_dist[t];
        int   bi = s_idx[t];
#pragma unroll
        for (int w = 1; w < 4; ++w) {
            const float ob = s_dist[w * 64 + t];
            const int   oi = s_idx[w * 64 + t];
            // quarters visited in ascending-k order; strict < keeps lowest k on ties
            if (ob < bb) { bb = ob; bi = oi; }
        }
        s_code[t] = bi;
    }
    __syncthreads();

    // ---- coalesced transpose epilogue ----
    // 16 lanes cover one row (16 x float4 = 256B); consecutive threads write
    // consecutive 16B chunks -> fully coalesced 1KB/wave stores. x re-read
    // from global (L2/L3-hot from the staging read).
    const int c   = t & 15;      // float4 chunk within row
    const int r0i = t >> 4;      // base row 0..15
    float lacc = 0.f;
#pragma unroll
    for (int i = 0; i < 4; ++i) {
        const int r = r0i + 16 * i;
        const int code = s_code[r];
        const float4 q = *(const float4*)(eT + (size_t)code * D + 4 * c);
        const float4 b = *(const float4*)(x + (rowbase + r) * D + 4 * c);
        const float f0 = __fsub_rn(b.x, q.x), f1 = __fsub_rn(b.y, q.y);
        const float f2 = __fsub_rn(b.z, q.z), f3 = __fsub_rn(b.w, q.w);
        lacc = fmaf(f0, f0, lacc); lacc = fmaf(f1, f1, lacc);
        lacc = fmaf(f2, f2, lacc); lacc = fmaf(f3, f3, lacc);
        float4 o;
        o.x = __fadd_rn(b.x, __fsub_rn(q.x, b.x));
        o.y = __fadd_rn(b.y, __fsub_rn(q.y, b.y));
        o.z = __fadd_rn(b.z, __fsub_rn(q.z, b.z));
        o.w = __fadd_rn(b.w, __fsub_rn(q.w, b.w));
        *(float4*)(out + (rowbase + r) * D + 4 * c) = o;
    }

    // ---- block loss reduction ----
#pragma unroll
    for (int off = 32; off > 0; off >>= 1) lacc += __shfl_down(lacc, off);
    if (lane == 0) s_red[wave] = lacc;
    __syncthreads();
    if (t == 0) partials[blockIdx.x] = (s_red[0] + s_red[1]) + (s_red[2] + s_red[3]);
}

__global__ __launch_bounds__(256) void vq_finish(const float* __restrict__ partials,
                                                 float* __restrict__ loss_out) {
    __shared__ float s_red[4];
    const int t = threadIdx.x;
    float a = 0.f;
#pragma unroll
    for (int i = 0; i < 8; ++i) a += partials[t + 256 * i];   // NBLK=2048
#pragma unroll
    for (int off = 32; off > 0; off >>= 1) a += __shfl_down(a, off);
    if ((t & 63) == 0) s_red[t >> 6] = a;
    __syncthreads();
    if (t == 0) {
        const float S = (s_red[0] + s_red[1]) + (s_red[2] + s_red[3]);
        const float m = S / (float)NOUT;
        loss_out[0] = m + 0.25f * m;   // mean + BETA*mean
    }
}

extern "C" void kernel_launch(void* const* d_in, const int* in_sizes, int n_in,
                              void* d_out, int out_size, void* d_ws, size_t ws_size,
                              hipStream_t stream) {
    const float* x   = (const float*)d_in[0];
    const float* emb = (const float*)d_in[1];
    float* out = (float*)d_out;
    float* ws  = (float*)d_ws;

    float* eT       = ws;
    float* enorm    = ws + 32768;
    float* partials = ws + 32768 + 512;

    vq_prep<<<2, 256, 0, stream>>>(emb, eT, enorm);
    vq_main<<<NBLK, 256, 0, stream>>>(x, eT, enorm, out, partials);
    vq_finish<<<1, 256, 0, stream>>>(partials, out + NOUT);
}